// Round 9
// baseline (34.483 us; speedup 1.0000x reference)
//
#include <hip/hip_runtime.h>
#include <math.h>

// OSDT: soft decision tree leaf probabilities (round-3 structure, weights
// read directly through L1 — no LDS at all).
// x:[B,512] f32, w:[10,512] f32, thr:[10], lt:[10]  ->  out:[B,1024] f32
// Memory-bound: 33.6 MB read + 67 MB write => ~15.4 us bus floor.
//
// R4: kernel split serializes HBM phases (29 us) — stay monolithic.
// R5: 2 rows/thread halves waves/CU, regresses (22.8) — keep 1 row/subgroup.
// R7: non-temporal hints neutral (20.8) — traffic policy not the limiter.
// R8: the exposed term is the LDS dot stream: 16 waves x 80 ds_read_b128
//     x ~12cyc ~= 6.8 us/CU of DS-pipe time. The 20 KiB weight matrix fits
//     L1 (32 KiB/CU): read it directly from global — every read is an L1
//     hit (~2 us/CU on the TA path), DS pipe drops to zero, and the
//     staging loop + __syncthreads() disappear. x stays NT (keeps L1 free
//     for weights); stores stay NT.

#define IDIM   512
#define DEPTH  10
#define NLEAF  1024

typedef float f32x4 __attribute__((ext_vector_type(4)));

__global__ __launch_bounds__(256, 4) void osdt_kernel(
    const float* __restrict__ x,
    const float* __restrict__ sw,
    const float* __restrict__ thr,
    const float* __restrict__ lt,
    float* __restrict__ out,
    int batch)
{
    const int lane = threadIdx.x & 63;
    const int wave = threadIdx.x >> 6;
    const int g    = lane & 15;                 // lane within subgroup
    const int sg   = lane >> 4;                 // subgroup 0..3
    const int row  = blockIdx.x * 16 + wave * 4 + sg;
    const int crow = row < batch ? row : batch - 1;   // clamped for loads

    // Issue all 8 x-loads first (32 elems/lane, non-temporal: read-once
    // stream, keep it out of L1/L2 so the weights stay resident).
    f32x4 xv[8];
    {
        const f32x4* xr = reinterpret_cast<const f32x4*>(x + (size_t)crow * IDIM);
        #pragma unroll
        for (int c = 0; c < 8; ++c)
            xv[c] = __builtin_nontemporal_load(&xr[c * 16 + g]);
    }

    float thrv[DEPTH], sclv[DEPTH];
    #pragma unroll
    for (int d = 0; d < DEPTH; ++d) {
        thrv[d] = thr[d];
        sclv[d] = __expf(-lt[d]);
    }

    // Per-depth partial dots; weights read directly from global. All
    // subgroups (and all waves on the CU) read identical addresses: after
    // warm-up these are pure L1 hits (20 KiB matrix < 32 KiB L1), 4 cache
    // lines per instruction. No LDS, no barrier.
    const f32x4* wr = reinterpret_cast<const f32x4*>(sw);
    float part[DEPTH];
    #pragma unroll
    for (int d = 0; d < DEPTH; ++d) {
        float a0 = 0.0f, a1 = 0.0f;
        #pragma unroll
        for (int c = 0; c < 8; c += 2) {
            const f32x4 w0 = wr[d * 128 + c * 16 + g];
            const f32x4 w1 = wr[d * 128 + (c + 1) * 16 + g];
            a0 += xv[c].x * w0.x + xv[c].y * w0.y +
                  xv[c].z * w0.z + xv[c].w * w0.w;
            a1 += xv[c + 1].x * w1.x + xv[c + 1].y * w1.y +
                  xv[c + 1].z * w1.z + xv[c + 1].w * w1.w;
        }
        part[d] = a0 + a1;
    }

    // 4-step butterfly within the 16-lane subgroup (masks 1/2/4/8, VALU
    // DPP-class); result broadcast to all 16 lanes.
    #pragma unroll
    for (int d = 0; d < DEPTH; ++d) {
        #pragma unroll
        for (int m = 1; m < 16; m <<= 1)
            part[d] += __shfl_xor(part[d], m, 64);
    }

    // Sigmoids. Clamp |z|<=30: |dot| can reach ~100 and expf overflows to
    // inf (inf*0 = NaN). sigmoid(30)=1-9e-14 << 2e-2 tolerance.
    float lv[DEPTH], rv[DEPTH];
    #pragma unroll
    for (int d = 0; d < DEPTH; ++d) {
        float z = (part[d] - thrv[d]) * sclv[d];
        z = fminf(fmaxf(z, -30.0f), 30.0f);
        const float e  = __expf(-z);
        const float rr = 1.0f / (1.0f + e);   // sigmoid(z)
        rv[d] = rr;
        lv[d] = e * rr;                       // sigmoid(-z)
    }

    // Leaf l = c*64 + g*4 + k:
    //   bits 0,1 = k  -> depths 0,1 (head)
    //   bits 2..5 = g -> depths 2..5 (base, lane-specific)
    //   bits 6..9 = c -> depths 6..9 (t67 x t89)
    float base = ((g & 1) ? rv[2] : lv[2]) * ((g & 2) ? rv[3] : lv[3]) *
                 ((g & 4) ? rv[4] : lv[4]) * ((g & 8) ? rv[5] : lv[5]);
    float hb[4];
    hb[0] = lv[0] * lv[1] * base;  hb[1] = rv[0] * lv[1] * base;
    hb[2] = lv[0] * rv[1] * base;  hb[3] = rv[0] * rv[1] * base;
    float t67[4], t89[4];
    t67[0] = lv[6] * lv[7];  t67[1] = rv[6] * lv[7];
    t67[2] = lv[6] * rv[7];  t67[3] = rv[6] * rv[7];
    t89[0] = lv[8] * lv[9];  t89[1] = rv[8] * lv[9];
    t89[2] = lv[8] * rv[9];  t89[3] = rv[8] * rv[9];

    if (row >= batch) return;

    // 16 non-temporal float4 stores (write-once stream, skip L2 allocation).
    // Subgroup writes 256B-contiguous segments.
    float* orow = out + (size_t)row * NLEAF;
    #pragma unroll
    for (int c = 0; c < 16; ++c) {
        const float t = t67[c & 3] * t89[c >> 2];   // c compile-time
        f32x4 v;
        v.x = hb[0] * t;
        v.y = hb[1] * t;
        v.z = hb[2] * t;
        v.w = hb[3] * t;
        __builtin_nontemporal_store(
            v, reinterpret_cast<f32x4*>(orow + c * 64 + g * 4));
    }
}

extern "C" void kernel_launch(void* const* d_in, const int* in_sizes, int n_in,
                              void* d_out, int out_size, void* d_ws, size_t ws_size,
                              hipStream_t stream) {
    const float* x   = (const float*)d_in[0];
    const float* sw  = (const float*)d_in[1];
    const float* thr = (const float*)d_in[2];
    const float* lt  = (const float*)d_in[3];
    float* out = (float*)d_out;

    const int batch  = in_sizes[0] / IDIM;        // 16384
    const int blocks = (batch + 15) / 16;         // 1024 (16 rows/block)

    osdt_kernel<<<blocks, 256, 0, stream>>>(x, sw, thr, lt, out, batch);
}

// Round 10
// 20.503 us; speedup vs baseline: 1.6819x; 1.6819x over previous
//
#include <hip/hip_runtime.h>
#include <math.h>

// OSDT: soft decision tree leaf probabilities.
// x:[B,512] f32, w:[10,512] f32, thr:[10], lt:[10]  ->  out:[B,1024] f32
// Memory-bound: ~23-34 MB read (partially L3-resident) + 67 MB write
// => ~14-15.5 us bus floor.
//
// Ledger of attempts:
//  R4: kernel split serializes HBM phases (29 us) — stay monolithic.
//  R5: 2 rows/thread halves waves/CU, regresses (22.8) — keep 1 row/subgroup,
//      16 waves/CU.
//  R7: non-temporal load/store hints neutral (20.8) — allocation policy is
//      not the limiter.
//  R8: weights direct from L1 (no LDS): 34.5 us, VALUBusy 11%, occ 24% —
//      latency-bound; LDS staging is latency insulation. Reverted.
//  R9: the reduction shfl ops also ran on the DS pipe (ds_bpermute): 40/thread
//      on top of 80 ds_read_b128. Replace the 16-lane butterfly with pure-VALU
//      DPP adds (quad_perm xor1/xor2, row_half_mirror, row_mirror — each step
//      exchanges complementary halves, so the sum broadcasts to all 16 lanes).
//      Zero DS ops, no occupancy change.

#define IDIM   512
#define DEPTH  10
#define NLEAF  1024

typedef float f32x4 __attribute__((ext_vector_type(4)));

// v += dpp_perm(v): butterfly step using a half-exchanging involution.
// CTRL: 0xB1 = quad_perm[1,0,3,2] (xor1), 0x4E = quad_perm[2,3,0,1] (xor2),
// 0x141 = row_half_mirror (exchanges 4-groups within 8),
// 0x140 = row_mirror (exchanges 8-halves within the 16-lane DPP row).
template<int CTRL>
__device__ __forceinline__ float dpp_add(float v) {
    const int s = __builtin_amdgcn_update_dpp(
        0, __float_as_int(v), CTRL, 0xF, 0xF, true);
    return v + __int_as_float(s);
}

__global__ __launch_bounds__(256, 4) void osdt_kernel(
    const float* __restrict__ x,
    const float* __restrict__ sw,
    const float* __restrict__ thr,
    const float* __restrict__ lt,
    float* __restrict__ out,
    int batch)
{
    __shared__ float4 s_w4[DEPTH * IDIM / 4];   // 1280 float4 = 20 KiB

    const int lane = threadIdx.x & 63;
    const int wave = threadIdx.x >> 6;
    const int g    = lane & 15;                 // lane within subgroup
    const int sg   = lane >> 4;                 // subgroup 0..3 (= DPP rows? no:
                                                // DPP row = 16 lanes, subgroup
                                                // IS one DPP row)
    const int row  = blockIdx.x * 16 + wave * 4 + sg;
    const int crow = row < batch ? row : batch - 1;   // clamped for loads

    // Issue all 8 x-loads first (32 elems/lane, normal cached loads — x is
    // L3-resident across replays; NT reads forfeit that, per R8).
    float4 xv[8];
    {
        const float4* xr = reinterpret_cast<const float4*>(x + (size_t)crow * IDIM);
        #pragma unroll
        for (int c = 0; c < 8; ++c)
            xv[c] = xr[c * 16 + g];
    }

    // Stage the 20 KiB weight matrix into LDS (overlaps with the x loads).
    {
        const float4* src = reinterpret_cast<const float4*>(sw);
        #pragma unroll
        for (int i = 0; i < 5; ++i)
            s_w4[threadIdx.x + i * 256] = src[threadIdx.x + i * 256];
    }
    float thrv[DEPTH], sclv[DEPTH];
    #pragma unroll
    for (int d = 0; d < DEPTH; ++d) {
        thrv[d] = thr[d];
        sclv[d] = __expf(-lt[d]);
    }
    __syncthreads();

    // Per-depth partial dots: weights streamed from LDS (subgroups 0..3 read
    // identical addresses -> broadcast; 16 lanes x 16B = 2-way aliasing = free).
    float part[DEPTH];
    #pragma unroll
    for (int d = 0; d < DEPTH; ++d) {
        float a0 = 0.0f, a1 = 0.0f;
        #pragma unroll
        for (int c = 0; c < 8; c += 2) {
            const float4 w0 = s_w4[d * 128 + c * 16 + g];
            const float4 w1 = s_w4[d * 128 + (c + 1) * 16 + g];
            a0 += xv[c].x * w0.x + xv[c].y * w0.y +
                  xv[c].z * w0.z + xv[c].w * w0.w;
            a1 += xv[c + 1].x * w1.x + xv[c + 1].y * w1.y +
                  xv[c + 1].z * w1.z + xv[c + 1].w * w1.w;
        }
        part[d] = a0 + a1;
    }

    // Pure-VALU butterfly within the 16-lane subgroup (one DPP row).
    // Each step adds the complementary half's partial sum; after 4 steps
    // every lane holds the full 16-lane sum. No DS-pipe ops.
    #pragma unroll
    for (int d = 0; d < DEPTH; ++d) {
        float p = part[d];
        p = dpp_add<0xB1>(p);    // quad_perm [1,0,3,2]
        p = dpp_add<0x4E>(p);    // quad_perm [2,3,0,1]
        p = dpp_add<0x141>(p);   // row_half_mirror
        p = dpp_add<0x140>(p);   // row_mirror
        part[d] = p;
    }

    // Sigmoids. Clamp |z|<=30: |dot| can reach ~100 and expf overflows to
    // inf (inf*0 = NaN). sigmoid(30)=1-9e-14 << 2e-2 tolerance.
    float lv[DEPTH], rv[DEPTH];
    #pragma unroll
    for (int d = 0; d < DEPTH; ++d) {
        float z = (part[d] - thrv[d]) * sclv[d];
        z = fminf(fmaxf(z, -30.0f), 30.0f);
        const float e  = __expf(-z);
        const float rr = 1.0f / (1.0f + e);   // sigmoid(z)
        rv[d] = rr;
        lv[d] = e * rr;                       // sigmoid(-z)
    }

    // Leaf l = c*64 + g*4 + k:
    //   bits 0,1 = k  -> depths 0,1 (head)
    //   bits 2..5 = g -> depths 2..5 (base, lane-specific)
    //   bits 6..9 = c -> depths 6..9 (t67 x t89)
    float base = ((g & 1) ? rv[2] : lv[2]) * ((g & 2) ? rv[3] : lv[3]) *
                 ((g & 4) ? rv[4] : lv[4]) * ((g & 8) ? rv[5] : lv[5]);
    float hb[4];
    hb[0] = lv[0] * lv[1] * base;  hb[1] = rv[0] * lv[1] * base;
    hb[2] = lv[0] * rv[1] * base;  hb[3] = rv[0] * rv[1] * base;
    float t67[4], t89[4];
    t67[0] = lv[6] * lv[7];  t67[1] = rv[6] * lv[7];
    t67[2] = lv[6] * rv[7];  t67[3] = rv[6] * rv[7];
    t89[0] = lv[8] * lv[9];  t89[1] = rv[8] * lv[9];
    t89[2] = lv[8] * rv[9];  t89[3] = rv[8] * rv[9];

    if (row >= batch) return;

    // 16 non-temporal float4 stores (write-once stream; tested neutral,
    // keeps L2 clean for x). Subgroup writes 256B-contiguous segments.
    float* orow = out + (size_t)row * NLEAF;
    #pragma unroll
    for (int c = 0; c < 16; ++c) {
        const float t = t67[c & 3] * t89[c >> 2];   // c compile-time
        f32x4 v;
        v.x = hb[0] * t;
        v.y = hb[1] * t;
        v.z = hb[2] * t;
        v.w = hb[3] * t;
        __builtin_nontemporal_store(
            v, reinterpret_cast<f32x4*>(orow + c * 64 + g * 4));
    }
}

extern "C" void kernel_launch(void* const* d_in, const int* in_sizes, int n_in,
                              void* d_out, int out_size, void* d_ws, size_t ws_size,
                              hipStream_t stream) {
    const float* x   = (const float*)d_in[0];
    const float* sw  = (const float*)d_in[1];
    const float* thr = (const float*)d_in[2];
    const float* lt  = (const float*)d_in[3];
    float* out = (float*)d_out;

    const int batch  = in_sizes[0] / IDIM;        // 16384
    const int blocks = (batch + 15) / 16;         // 1024 (16 rows/block)

    osdt_kernel<<<blocks, 256, 0, stream>>>(x, sw, thr, lt, out, batch);
}

// Round 11
// 20.393 us; speedup vs baseline: 1.6909x; 1.0054x over previous
//
#include <hip/hip_runtime.h>
#include <math.h>

// OSDT: soft decision tree leaf probabilities.
// x:[B,512] f32, w:[10,512] f32, thr:[10], lt:[10]  ->  out:[B,1024] f32
// Memory-bound: ~23-34 MB read (x partially L3-resident) + 67 MB write
// => ~14-15.5 us bus floor.
//
// Ledger:
//  R4: kernel split serializes HBM phases (29 us) — stay monolithic.
//  R5: 2 rows/thread at 8 waves/CU regresses (22.8) — TLP matters.
//  R7: non-temporal hints neutral (20.8) — allocation policy not the limiter.
//  R8: L1-direct weights: 34.5 us, occ 24% — latency-bound; LDS staging is
//      latency insulation. Reverted.
//  R9: DPP butterfly neutral (20.5) — DS pipe was already hidden.
//  R10: the untested lever is OCCUPANCY (R8 showed 24%; R3>R5 shows dur is
//       monotone in waves/CU; we've never exceeded 16 waves/CU). Switch to
//       32-lane subgroups: 4 float4 x-fragments/lane (16 VGPR), peak ~55
//       VGPR, capped at 64 via __launch_bounds__(1024,8) -> 32 waves/CU
//       (hardware max), 2 blocks/CU, 40 KiB LDS/CU. Reduction = 4 DPP steps
//       + ds_swizzle(lane^16). Same single-shot structure otherwise.

#define IDIM   512
#define DEPTH  10
#define NLEAF  1024

typedef float f32x4 __attribute__((ext_vector_type(4)));

// v += dpp_perm(v): butterfly step with a half-exchanging involution
// (verified R9). 0xB1=quad_perm[1,0,3,2] (xor1), 0x4E=quad_perm[2,3,0,1]
// (xor2), 0x141=row_half_mirror (xor4), 0x140=row_mirror (xor8).
template<int CTRL>
__device__ __forceinline__ float dpp_add(float v) {
    const int s = __builtin_amdgcn_update_dpp(
        0, __float_as_int(v), CTRL, 0xF, 0xF, true);
    return v + __int_as_float(s);
}
// lane ^= 16 within each 32-lane half: ds_swizzle BitMode
// offset = (xor=16)<<10 | (or=0)<<5 | (and=0x1F) = 0x401F.
__device__ __forceinline__ float swz_add16(float v) {
    const int s = __builtin_amdgcn_ds_swizzle(__float_as_int(v), 0x401F);
    return v + __int_as_float(s);
}

__global__ __launch_bounds__(1024, 8) void osdt_kernel(
    const float* __restrict__ x,
    const float* __restrict__ sw,
    const float* __restrict__ thr,
    const float* __restrict__ lt,
    float* __restrict__ out,
    int batch)
{
    __shared__ float4 s_w4[DEPTH * IDIM / 4];   // 1280 float4 = 20 KiB

    const int tid  = threadIdx.x;
    const int lane = tid & 63;
    const int wave = tid >> 6;                  // 0..15
    const int l32  = lane & 31;                 // lane within 32-subgroup
    const int h    = lane >> 5;                 // which half-wave (row)
    const int row  = blockIdx.x * 32 + wave * 2 + h;
    const int crow = row < batch ? row : batch - 1;   // clamped for loads

    // Issue all 4 x-loads first (16 elems/lane; 512B-contiguous per
    // subgroup chunk). Cached loads — x is partially L3-resident (R8).
    float4 xv[4];
    {
        const float4* xr = reinterpret_cast<const float4*>(x + (size_t)crow * IDIM);
        #pragma unroll
        for (int c = 0; c < 4; ++c)
            xv[c] = xr[c * 32 + l32];
    }

    // Stage the 20 KiB weight matrix into LDS (1024 threads: 1 full pass +
    // 256-thread tail; overlaps with the x loads).
    {
        const float4* src = reinterpret_cast<const float4*>(sw);
        s_w4[tid] = src[tid];
        if (tid < DEPTH * IDIM / 4 - 1024)
            s_w4[1024 + tid] = src[1024 + tid];
    }
    __syncthreads();

    // Per-depth partial dots: weights streamed from LDS (the two half-waves
    // read identical addresses -> broadcast).
    float part[DEPTH];
    #pragma unroll
    for (int d = 0; d < DEPTH; ++d) {
        float a0 = 0.0f, a1 = 0.0f;
        #pragma unroll
        for (int c = 0; c < 4; c += 2) {
            const float4 w0 = s_w4[d * 128 + c * 32 + l32];
            const float4 w1 = s_w4[d * 128 + (c + 1) * 32 + l32];
            a0 += xv[c].x * w0.x + xv[c].y * w0.y +
                  xv[c].z * w0.z + xv[c].w * w0.w;
            a1 += xv[c + 1].x * w1.x + xv[c + 1].y * w1.y +
                  xv[c + 1].z * w1.z + xv[c + 1].w * w1.w;
        }
        part[d] = a0 + a1;
    }

    // Butterfly reduce within the 32-lane subgroup: 4 pure-VALU DPP steps
    // (within the 16-lane DPP row) + one ds_swizzle for lane^16; result
    // broadcast to all 32 lanes.
    #pragma unroll
    for (int d = 0; d < DEPTH; ++d) {
        float p = part[d];
        p = dpp_add<0xB1>(p);    // xor1
        p = dpp_add<0x4E>(p);    // xor2
        p = dpp_add<0x141>(p);   // xor4 (row_half_mirror)
        p = dpp_add<0x140>(p);   // xor8 (row_mirror)
        p = swz_add16(p);        // xor16 (ds_swizzle 0x401F)
        part[d] = p;
    }

    // Sigmoids. Clamp |z|<=30: |dot| can reach ~100 and expf overflows to
    // inf (inf*0 = NaN). sigmoid(30)=1-9e-14 << 2e-2 tolerance.
    float lv[DEPTH], rv[DEPTH];
    #pragma unroll
    for (int d = 0; d < DEPTH; ++d) {
        float z = (part[d] - thr[d]) * __expf(-lt[d]);   // thr/lt: SGPR loads
        z = fminf(fmaxf(z, -30.0f), 30.0f);
        const float e  = __expf(-z);
        const float rr = 1.0f / (1.0f + e);   // sigmoid(z)
        rv[d] = rr;
        lv[d] = e * rr;                       // sigmoid(-z)
    }

    // Leaf l = c*128 + l32*4 + k:
    //   bits 0,1  = k   -> depths 0,1 (head)
    //   bits 2..6 = l32 -> depths 2..6 (base, lane-specific)
    //   bits 7..9 = c   -> depths 7..9 (rv/lv[7] x t89)
    const float base =
        ((l32 &  1) ? rv[2] : lv[2]) * ((l32 &  2) ? rv[3] : lv[3]) *
        ((l32 &  4) ? rv[4] : lv[4]) * ((l32 &  8) ? rv[5] : lv[5]) *
        ((l32 & 16) ? rv[6] : lv[6]);
    float hb[4];
    hb[0] = lv[0] * lv[1] * base;  hb[1] = rv[0] * lv[1] * base;
    hb[2] = lv[0] * rv[1] * base;  hb[3] = rv[0] * rv[1] * base;
    float t89[4];
    t89[0] = lv[8] * lv[9];  t89[1] = rv[8] * lv[9];
    t89[2] = lv[8] * rv[9];  t89[3] = rv[8] * rv[9];

    if (row >= batch) return;

    // 8 non-temporal float4 stores; each half-wave writes 512B-contiguous
    // segments (write-once stream, skip L2 allocation — tested neutral).
    float* orow = out + (size_t)row * NLEAF;
    #pragma unroll
    for (int c = 0; c < 8; ++c) {
        const float t = ((c & 1) ? rv[7] : lv[7]) * t89[c >> 1];  // c const
        f32x4 v;
        v.x = hb[0] * t;
        v.y = hb[1] * t;
        v.z = hb[2] * t;
        v.w = hb[3] * t;
        __builtin_nontemporal_store(
            v, reinterpret_cast<f32x4*>(orow + c * 128 + l32 * 4));
    }
}

extern "C" void kernel_launch(void* const* d_in, const int* in_sizes, int n_in,
                              void* d_out, int out_size, void* d_ws, size_t ws_size,
                              hipStream_t stream) {
    const float* x   = (const float*)d_in[0];
    const float* sw  = (const float*)d_in[1];
    const float* thr = (const float*)d_in[2];
    const float* lt  = (const float*)d_in[3];
    float* out = (float*)d_out;

    const int batch  = in_sizes[0] / IDIM;        // 16384
    const int blocks = (batch + 31) / 32;         // 512 (32 rows/block)

    osdt_kernel<<<blocks, 1024, 0, stream>>>(x, sw, thr, lt, out, batch);
}